// Round 25
// baseline (92.333 us; speedup 1.0000x reference)
//
#include <hip/hip_runtime.h>
#include <hip/hip_bf16.h>
#include <stdint.h>

// Problem constants
#define BB 16
#define SS 512
#define TT 16
#define DD 128
#define CH 64                 // s-rows per chunk
#define NCH (SS/CH)           // 8
#define LN_EPS 1e-5f

typedef __attribute__((ext_vector_type(8))) short short8;
typedef __attribute__((ext_vector_type(4))) float f32x4;

// HW packed f32->bf16 (RNE): dst.lo = src0, dst.hi = src1
static __device__ __forceinline__ uint32_t cvt_pk_bf16(float lo, float hi) {
    uint32_t r;
    asm("v_cvt_pk_bf16_f32 %0, %1, %2" : "=v"(r) : "v"(lo), "v"(hi));
    return r;
}

#define BAR() do {                                            \
    asm volatile("s_waitcnt lgkmcnt(0)" ::: "memory");        \
    __builtin_amdgcn_s_barrier();                             \
    asm volatile("" ::: "memory");                            \
} while (0)

// -----------------------------------------------------------------------------
// Two-pass chunk-parallel scan. Grid = 2048 blocks (one per (b,t,chunk)),
// 512 threads = 8 waves, 2 blocks/CU -> 4 free-running waves/SIMD, ONE barrier
// per block. The serial 512-step recurrence is decomposed across chunks via
// affine composites (Mc,Mv) in ws (2 MB):
//   PASS 1: LN+GEMM+act+local scan -> write chunk composite only.
//   PASS 2: recompute chunk (GEMM at 4% util - recompute is free), fold
//           h_start from predecessors' composites (<=7 FMAs), store out.
// Same compose algebra as r12 -> identical rounding path.
// Wave w owns cols [w*16,w*16+16) (gate) and +128 (hidden); row permutation
// s = lhi*16+mt*4+j <-> A-slot mt*16+lhi*4+j; bank-swizzled LDS as r12.
// -----------------------------------------------------------------------------
template<int PASS>
__global__ __launch_bounds__(512, 4)
void mingru_pass(
    const float* __restrict__ x, const float* __restrict__ prevh,
    const float* __restrict__ gamma, const float* __restrict__ beta,
    const float* __restrict__ W, const float* __restrict__ bias,
    float2* __restrict__ cws, float* __restrict__ out,
    float* __restrict__ nexth)
{
    __shared__ __align__(16) unsigned char xnb[CH*256];     // 16 KB bf16 xn

    const int tid  = threadIdx.x;
    const int w    = tid >> 6;           // 0..7
    const int lane = tid & 63;
    const int l15  = lane & 15;
    const int lhi  = lane >> 4;

    const int bid = blockIdx.x;
    const int bt  = bid >> 3;            // (b,t) chain
    const int ch  = bid & 7;             // chunk within the chain
    const size_t rowstride = (size_t)TT * DD;               // 2048
    const size_t base_bt   = ((size_t)(bt >> 4) * SS * TT + (bt & 15)) * DD;

    // ---- LN lane assignment: 8 threads per row ----
    const int r_ln = tid >> 3;           // s-row 0..63 within chunk
    const int c8   = tid & 7;            // 16-float slot within the row
    const int slot_p = ((r_ln >> 2) & 3)*16 + (r_ln >> 4)*4 + (r_ln & 3);
    const int keyx   = slot_p & 7;

    // ---- x load for this block's chunk (issued first, 16 VGPR) ----
    const float* xp = x + base_bt + (size_t)(ch*CH + r_ln)*rowstride + c8*16;
    const f32x4 px0 = *(const f32x4*)(xp + 0);
    const f32x4 px1 = *(const f32x4*)(xp + 4);
    const f32x4 px2 = *(const f32x4*)(xp + 8);
    const f32x4 px3 = *(const f32x4*)(xp + 12);

    // ---- build W fragments + folded bias (hides the x-load latency) ----
    short8 wfr[2][4];
    float  bs2[2];
    #pragma unroll
    for (int ni = 0; ni < 2; ++ni) {
        const int col = (ni ? 128 : 0) + w*16 + l15;
        float acc = 0.0f;
        #pragma unroll
        for (int kt = 0; kt < 4; ++kt) {
            union { short8 s8; uint32_t u[4]; } fr;
            #pragma unroll
            for (int p = 0; p < 4; ++p) {
                const int k0 = kt*32 + lhi*8 + 2*p;
                const float w0 = W[(size_t)k0*256 + col];
                const float w1 = W[(size_t)(k0+1)*256 + col];
                acc = fmaf(beta[k0],   w0, acc);
                acc = fmaf(beta[k0+1], w1, acc);
                fr.u[p] = cvt_pk_bf16(gamma[k0]*w0, gamma[k0+1]*w1);
            }
            wfr[ni][kt] = fr.s8;
        }
        acc += __shfl_xor(acc, 16);
        acc += __shfl_xor(acc, 32);
        bs2[ni] = bias[col] + acc;
    }

    // ---- LN -> xnb at permuted slot (swizzled) ----
    {
        float s1 = px0.x+px0.y+px0.z+px0.w + px1.x+px1.y+px1.z+px1.w
                 + px2.x+px2.y+px2.z+px2.w + px3.x+px3.y+px3.z+px3.w;
        float s2 = px0.x*px0.x+px0.y*px0.y+px0.z*px0.z+px0.w*px0.w
                 + px1.x*px1.x+px1.y*px1.y+px1.z*px1.z+px1.w*px1.w
                 + px2.x*px2.x+px2.y*px2.y+px2.z*px2.z+px2.w*px2.w
                 + px3.x*px3.x+px3.y*px3.y+px3.z*px3.z+px3.w*px3.w;
        s1 += __shfl_xor(s1, 1); s2 += __shfl_xor(s2, 1);
        s1 += __shfl_xor(s1, 2); s2 += __shfl_xor(s2, 2);
        s1 += __shfl_xor(s1, 4); s2 += __shfl_xor(s2, 4);
        const float mu = s1 * (1.0f/128.0f);
        const float rs = rsqrtf(s2 * (1.0f/128.0f) - mu*mu + LN_EPS);
        unsigned char* row = xnb + slot_p*256;
        union { short8 s8; uint32_t u[4]; } a, b2;
        a.u[0]  = cvt_pk_bf16((px0.x-mu)*rs, (px0.y-mu)*rs);
        a.u[1]  = cvt_pk_bf16((px0.z-mu)*rs, (px0.w-mu)*rs);
        a.u[2]  = cvt_pk_bf16((px1.x-mu)*rs, (px1.y-mu)*rs);
        a.u[3]  = cvt_pk_bf16((px1.z-mu)*rs, (px1.w-mu)*rs);
        b2.u[0] = cvt_pk_bf16((px2.x-mu)*rs, (px2.y-mu)*rs);
        b2.u[1] = cvt_pk_bf16((px2.z-mu)*rs, (px2.w-mu)*rs);
        b2.u[2] = cvt_pk_bf16((px3.x-mu)*rs, (px3.y-mu)*rs);
        b2.u[3] = cvt_pk_bf16((px3.z-mu)*rs, (px3.w-mu)*rs);
        *(short8*)(row + (((2*c8)     ^ keyx) << 4)) = a.s8;
        *(short8*)(row + (((2*c8 + 1) ^ keyx) << 4)) = b2.s8;
    }
    BAR();   // the only barrier in the block

    // ---- GEMM + activation -> Cc/Cv (s = lhi*16 + mt*4 + j) ----
    float Cc[16], Cv[16];
    #pragma unroll
    for (int mt = 0; mt < 4; ++mt) {
        const unsigned char* rowp = xnb + (mt*16 + l15)*256;
        short8 af[4];
        #pragma unroll
        for (int kt = 0; kt < 4; ++kt) {
            const int c = (kt << 2) | lhi;
            af[kt] = *(const short8*)(rowp + ((c ^ (l15 & 7)) << 4));
        }
        f32x4 ag = (f32x4)(0.f), ah = (f32x4)(0.f);
        #pragma unroll
        for (int kt = 0; kt < 4; ++kt) {
            ag = __builtin_amdgcn_mfma_f32_16x16x32_bf16(af[kt], wfr[0][kt], ag, 0, 0, 0);
            ah = __builtin_amdgcn_mfma_f32_16x16x32_bf16(af[kt], wfr[1][kt], ah, 0, 0, 0);
        }
        #pragma unroll
        for (int j = 0; j < 4; ++j) {
            const float g  = ag[j] + bs2[0];
            const float hh = ah[j] + bs2[1];
            const float cc = 1.0f / (1.0f + __expf(g));
            const float ga = (hh >= 0.0f) ? (hh + 0.5f)
                                          : (1.0f / (1.0f + __expf(-hh)));
            Cc[mt*4 + j] = cc;
            Cv[mt*4 + j] = (1.0f - cc) * ga;
        }
    }
    // lane-local inclusive prefix over 16 consecutive s-rows
    #pragma unroll
    for (int i = 1; i < 16; ++i) {
        Cv[i] = fmaf(Cc[i], Cv[i-1], Cv[i]);
        Cc[i] = Cc[i] * Cc[i-1];
    }
    // cross-lhi Hillis-Steele on 16-row composites
    float Ic = Cc[15], Iv = Cv[15];
    float pc = __shfl_up(Ic, 16), pv = __shfl_up(Iv, 16);
    if (lhi >= 1) { Iv = fmaf(Ic, pv, Iv); Ic *= pc; }
    pc = __shfl_up(Ic, 32); pv = __shfl_up(Iv, 32);
    if (lhi >= 2) { Iv = fmaf(Ic, pv, Iv); Ic *= pc; }
    const float Mc = __shfl(Ic, 48 + l15);   // full-chunk composite
    const float Mv = __shfl(Iv, 48 + l15);

    if constexpr (PASS == 1) {
        // publish chunk composite (128 float2 per block)
        if (lane < 16)
            cws[(size_t)bid*128 + w*16 + lane] = make_float2(Mc, Mv);
    } else {
        // exclusive prefix for this lhi group
        float Ec = __shfl_up(Ic, 16), Ev = __shfl_up(Iv, 16);
        if (lhi == 0) { Ec = 1.0f; Ev = 0.0f; }
        // fold h_start from predecessors' composites (<=7 serial FMAs)
        float h = prevh[(size_t)bt*128 + w*16 + l15];
        for (int k = 0; k < ch; ++k) {
            const float2 m = cws[((size_t)bt*8 + k)*128 + w*16 + l15];
            h = fmaf(m.x, h, m.y);
        }
        const float hE = fmaf(Ec, h, Ev);    // h before row lhi*16
        float* op = out + base_bt + (size_t)(ch*CH + lhi*16) * rowstride + w*16 + l15;
        #pragma unroll
        for (int i = 0; i < 16; ++i)
            op[(size_t)i * rowstride] = fmaf(Cc[i], hE, Cv[i]);
        if (ch == 7 && lane < 16)
            nexth[(size_t)bt*128 + w*16 + lane] = fmaf(Mc, h, Mv);
    }
}

extern "C" void kernel_launch(void* const* d_in, const int* in_sizes, int n_in,
                              void* d_out, int out_size, void* d_ws, size_t ws_size,
                              hipStream_t stream) {
    const float* x     = (const float*)d_in[0];
    const float* prevh = (const float*)d_in[1];
    const float* gamma = (const float*)d_in[2];
    const float* beta  = (const float*)d_in[3];
    const float* W     = (const float*)d_in[4];
    const float* bias  = (const float*)d_in[5];

    float* out   = (float*)d_out;
    float* nexth = out + (size_t)BB*SS*TT*DD;              // 16777216
    float2* cws  = (float2*)d_ws;                          // 2 MB composites

    mingru_pass<1><<<BB*TT*NCH, 512, 0, stream>>>(x, prevh, gamma, beta, W,
                                                  bias, cws, out, nexth);
    mingru_pass<2><<<BB*TT*NCH, 512, 0, stream>>>(x, prevh, gamma, beta, W,
                                                  bias, cws, out, nexth);
}